// Round 8
// baseline (1100.161 us; speedup 1.0000x reference)
//
#include <hip/hip_runtime.h>
#include <math.h>

#define D 512
#define HEADS 8
#define NLAYER 6
#define LSEQ 1024
#define BATCH 4
#define DKH 64
#define MTOK (BATCH*LSEQ)   // 4096 tokens
#define EPS 1e-5f
#define EMB_SCALE 22.627416997969522f  // sqrt(512)
#define INV_SCALE 0.125f               // 1/sqrt(64)

typedef __attribute__((ext_vector_type(8))) __bf16 bf16x8;
typedef __attribute__((ext_vector_type(4))) float f32x4;

__device__ __forceinline__ unsigned short f2bf(float x) {
    union { float f; unsigned u; } v; v.f = x;
    unsigned r = (v.u + 0x7FFFu + ((v.u >> 16) & 1u)) >> 16;
    return (unsigned short)r;
}
__device__ __forceinline__ unsigned pack2(float a, float b) {
    return (unsigned)f2bf(a) | ((unsigned)f2bf(b) << 16);
}
__device__ __forceinline__ void gl_lds16(const unsigned short* g, unsigned short* l) {
    __builtin_amdgcn_global_load_lds(
        (const __attribute__((address_space(1))) unsigned*)g,
        (__attribute__((address_space(3))) unsigned*)l, 16, 0, 0);
}

// ---------------- embedding + positional encoding (fp32 x) ----------------
__global__ __launch_bounds__(128) void embed_kernel(
    const int* __restrict__ tokens, const float* __restrict__ emb,
    float* __restrict__ x)
{
    int row = blockIdx.x;
    int pos = row & (LSEQ - 1);
    int tok = tokens[row];
    int c = threadIdx.x * 4;
    float4 e = *(const float4*)(emb + (size_t)tok * D + c);
    float o[4] = {e.x, e.y, e.z, e.w};
#pragma unroll
    for (int i = 0; i < 4; ++i) {
        int col = c + i;
        int ii = col & ~1;
        float dv = expf(-(float)ii * (9.210340371976184f / (float)D));
        float a = (float)pos * dv;
        float pe = (col & 1) ? cosf(a) : sinf(a);
        o[i] = o[i] * EMB_SCALE + pe;
    }
    float4 r; r.x = o[0]; r.y = o[1]; r.z = o[2]; r.w = o[3];
    *(float4*)(x + (size_t)row * D + c) = r;
}

// ---------------- layernorm fp32 -> bf16: one wave per row ----------------
__global__ __launch_bounds__(256) void ln_kernel(
    const float* __restrict__ x, const float* __restrict__ g,
    const float* __restrict__ b, unsigned short* __restrict__ h)
{
    int lane = threadIdx.x & 63;
    int row = blockIdx.x * 4 + (threadIdx.x >> 6);
    const float* xr = x + (size_t)row * D + lane * 8;
    float4 v0 = *(const float4*)(xr);
    float4 v1 = *(const float4*)(xr + 4);
    float s = v0.x + v0.y + v0.z + v0.w + v1.x + v1.y + v1.z + v1.w;
#pragma unroll
    for (int off = 32; off; off >>= 1) s += __shfl_xor(s, off, 64);
    float m = s * (1.0f / D);
    float d0 = v0.x - m, d1 = v0.y - m, d2 = v0.z - m, d3 = v0.w - m;
    float d4 = v1.x - m, d5 = v1.y - m, d6 = v1.z - m, d7 = v1.w - m;
    float ss = d0*d0 + d1*d1 + d2*d2 + d3*d3 + d4*d4 + d5*d5 + d6*d6 + d7*d7;
#pragma unroll
    for (int off = 32; off; off >>= 1) ss += __shfl_xor(ss, off, 64);
    float inv = rsqrtf(ss * (1.0f / D) + EPS);
    const float* gp = g + lane * 8;
    const float* bp = b + lane * 8;
    float4 g0 = *(const float4*)(gp), g1 = *(const float4*)(gp + 4);
    float4 b0 = *(const float4*)(bp), b1 = *(const float4*)(bp + 4);
    uint4 o;
    o.x = pack2(d0 * inv * g0.x + b0.x, d1 * inv * g0.y + b0.y);
    o.y = pack2(d2 * inv * g0.z + b0.z, d3 * inv * g0.w + b0.w);
    o.z = pack2(d4 * inv * g1.x + b1.x, d5 * inv * g1.y + b1.y);
    o.w = pack2(d6 * inv * g1.z + b1.z, d7 * inv * g1.w + b1.w);
    *(uint4*)(h + (size_t)row * D + lane * 8) = o;
}

// ---------------- per-layer weight fp32 -> bf16 (+ combined QKV bias) ----------------
__global__ __launch_bounds__(256) void wconv_kernel(
    const float* __restrict__ Wq, const float* __restrict__ Wkv,
    const float* __restrict__ Wo, const float* __restrict__ W1,
    const float* __restrict__ W2, const float* __restrict__ bq,
    const float* __restrict__ bkv, unsigned short* __restrict__ dst,
    float* __restrict__ bias_out)
{
    if (blockIdx.x == 1536) {
        for (int i = threadIdx.x; i < 1536; i += 256)
            bias_out[i] = (i < 512) ? bq[i] : bkv[i - 512];
        return;
    }
    int gid = blockIdx.x * 256 + threadIdx.x;
    int e = gid * 8;
    const float* src;
    if      (e < 262144)  src = Wq  + e;
    else if (e < 786432)  src = Wkv + (e - 262144);
    else if (e < 1048576) src = Wo  + (e - 786432);
    else if (e < 2097152) src = W1  + (e - 1048576);
    else                  src = W2  + (e - 2097152);
    float4 a = *(const float4*)src;
    float4 b = *(const float4*)(src + 4);
    uint4 o;
    o.x = pack2(a.x, a.y); o.y = pack2(a.z, a.w);
    o.z = pack2(b.x, b.y); o.w = pack2(b.z, b.w);
    *(uint4*)(dst + e) = o;
}

// ---------------- bf16 MFMA GEMM: acc = A(bf16 MxK) @ W(bf16 NxK)^T ----------------
// Tile BM x 128, BK=32, 256 threads. BM=128: waves 2x2 (64x64 each);
// BM=64: waves 1x4 (64x32 each).
// OMODE 0: C fp32 [M][N] = acc + bias + X (residual)
// OMODE 1: C bf16 [M][N] = relu(acc + bias)
// OMODE 2: fused QKV (N=1536): c<512 -> C=Qb[bh][t][64] scaled;
//          512<=c<1024 -> C2=Kb[bh][t][64]; c>=1024 -> C3=Vt[bh][d][t]
template<int OMODE, int BM>
__global__ __launch_bounds__(256) void gemm_bf16(
    const unsigned short* __restrict__ A, const unsigned short* __restrict__ W,
    const float* __restrict__ bias, const float* __restrict__ X,
    void* __restrict__ C, void* __restrict__ C2, void* __restrict__ C3,
    int M, int N, int K)
{
    constexpr int WM = BM / 64;       // 2 or 1
    constexpr int WN = 4 / WM;        // 2 or 4
    constexpr int NI = 8 / WN;        // 4 or 2 (16-col frags per wave)
    __shared__ unsigned short As[BM * 32];
    __shared__ unsigned short Bs[128 * 32];
    const int tid = threadIdx.x;
    const int wave = tid >> 6, lane = tid & 63;
    const int quad = lane >> 4, l16 = lane & 15;
    const int wm = wave / WN, wn = wave % WN;
    const int bm = blockIdx.y * BM, bn = blockIdx.x * 128;

    const int srow = wave * 16 + (lane >> 2);
    const int scol = (lane & 3) * 8;
    const unsigned short* Ag0 = A + (size_t)(bm + srow) * K + scol;
    const unsigned short* Ag1 = Ag0 + (size_t)64 * K;
    const unsigned short* Wg0 = W + (size_t)(bn + srow) * K + scol;
    const unsigned short* Wg1 = Wg0 + (size_t)64 * K;
    unsigned short* Al0 = As + wave * 512 + lane * 8;
    unsigned short* Al1 = Al0 + 2048;
    unsigned short* Bl0 = Bs + wave * 512 + lane * 8;
    unsigned short* Bl1 = Bl0 + 2048;

    f32x4 acc[4][NI];
#pragma unroll
    for (int mi = 0; mi < 4; ++mi)
#pragma unroll
        for (int ni = 0; ni < NI; ++ni) acc[mi][ni] = (f32x4){0.f, 0.f, 0.f, 0.f};

    for (int k0 = 0; k0 < K; k0 += 32) {
        __syncthreads();
        gl_lds16(Ag0 + k0, Al0);
        if (BM == 128) gl_lds16(Ag1 + k0, Al1);
        gl_lds16(Wg0 + k0, Bl0);
        gl_lds16(Wg1 + k0, Bl1);
        __syncthreads();
        bf16x8 af[4], bf[NI];
#pragma unroll
        for (int mi = 0; mi < 4; ++mi)
            af[mi] = *(const bf16x8*)(As + (wm * 64 + mi * 16 + l16) * 32 + quad * 8);
#pragma unroll
        for (int ni = 0; ni < NI; ++ni)
            bf[ni] = *(const bf16x8*)(Bs + (wn * (128 / WN) + ni * 16 + l16) * 32 + quad * 8);
#pragma unroll
        for (int mi = 0; mi < 4; ++mi)
#pragma unroll
            for (int ni = 0; ni < NI; ++ni)
                acc[mi][ni] = __builtin_amdgcn_mfma_f32_16x16x32_bf16(
                    af[mi], bf[ni], acc[mi][ni], 0, 0, 0);
    }

    const int er = bm + wm * 64;
    const int ec = bn + wn * (128 / WN);

    if (OMODE == 0) {
        float* Cf = (float*)C;
#pragma unroll
        for (int ni = 0; ni < NI; ++ni) {
            int c = ec + ni * 16 + l16;
            float bv = bias[c];
#pragma unroll
            for (int mi = 0; mi < 4; ++mi)
#pragma unroll
                for (int r = 0; r < 4; ++r) {
                    int m = er + mi * 16 + quad * 4 + r;
                    Cf[(size_t)m * N + c] = acc[mi][ni][r] + bv + X[(size_t)m * N + c];
                }
        }
    } else if (OMODE == 1) {
        unsigned short* Cb = (unsigned short*)C;
#pragma unroll
        for (int ni = 0; ni < NI; ++ni) {
            int c = ec + ni * 16 + l16;
            float bv = bias[c];
#pragma unroll
            for (int mi = 0; mi < 4; ++mi)
#pragma unroll
                for (int r = 0; r < 4; ++r) {
                    int m = er + mi * 16 + quad * 4 + r;
                    Cb[(size_t)m * N + c] = f2bf(fmaxf(acc[mi][ni][r] + bv, 0.f));
                }
        }
    } else {
        if (bn < 512) {            // Q (scaled)
            unsigned short* Qb = (unsigned short*)C;
#pragma unroll
            for (int ni = 0; ni < NI; ++ni) {
                int c = ec + ni * 16 + l16;
                float bv = bias[c];
                int hh = c >> 6, dd = c & 63;
#pragma unroll
                for (int mi = 0; mi < 4; ++mi)
#pragma unroll
                    for (int r = 0; r < 4; ++r) {
                        int m = er + mi * 16 + quad * 4 + r;
                        int b = m >> 10, t = m & 1023;
                        Qb[((size_t)(b * 8 + hh) * 1024 + t) * 64 + dd] =
                            f2bf((acc[mi][ni][r] + bv) * INV_SCALE);
                    }
            }
        } else if (bn < 1024) {    // K
            unsigned short* Kb = (unsigned short*)C2;
#pragma unroll
            for (int ni = 0; ni < NI; ++ni) {
                int c = ec + ni * 16 + l16;
                float bv = bias[c];
                int c2 = c - 512;
                int hh = c2 >> 6, dd = c2 & 63;
#pragma unroll
                for (int mi = 0; mi < 4; ++mi)
#pragma unroll
                    for (int r = 0; r < 4; ++r) {
                        int m = er + mi * 16 + quad * 4 + r;
                        int b = m >> 10, t = m & 1023;
                        Kb[((size_t)(b * 8 + hh) * 1024 + t) * 64 + dd] =
                            f2bf(acc[mi][ni][r] + bv);
                    }
            }
        } else {                   // V transposed
            unsigned short* Vt = (unsigned short*)C3;
#pragma unroll
            for (int ni = 0; ni < NI; ++ni) {
                int c = ec + ni * 16 + l16;
                float bv = bias[c];
                int c2 = c - 1024;
                int hh = c2 >> 6, dd = c2 & 63;
#pragma unroll
                for (int mi = 0; mi < 4; ++mi) {
                    int t0 = er + mi * 16 + quad * 4;
                    int b = t0 >> 10, tt = t0 & 1023;
                    ushort4 o;
                    o.x = f2bf(acc[mi][ni][0] + bv);
                    o.y = f2bf(acc[mi][ni][1] + bv);
                    o.z = f2bf(acc[mi][ni][2] + bv);
                    o.w = f2bf(acc[mi][ni][3] + bv);
                    *(ushort4*)(Vt + ((size_t)(b * 8 + hh) * 64 + dd) * 1024 + tt) = o;
                }
            }
        }
    }
}

// ---------------- flash attention: split-K across the block's 4 waves ----------------
// Qb,Kb: [32][1024][64] bf16 (Q pre-scaled); Vt: [32][64][1024] bf16.
// Block = 16 q-rows of one bh; wave w processes keys [w*256, w*256+256).
// Grid 2048 (32 bh x 64 q-tiles; bh = blockIdx%32 keeps K/V L2-resident per XCD).
// S^T = mfma(A=K,B=Q); register-only P transform via ds_bpermute (validated R7).
// Partials (fp32 O + denom) combined across waves through LDS with one barrier.
__global__ __launch_bounds__(256) void attn_mfma(
    const unsigned short* __restrict__ Qb, const unsigned short* __restrict__ Kb,
    const unsigned short* __restrict__ Vt, unsigned short* __restrict__ av)
{
    __shared__ float Ol[4][16][68];   // [wave][q][d] fp32 partial O (+pad)
    __shared__ float Ls[4][16];       // [wave][q] partial denominators
    const int tid = threadIdx.x;
    const int wave = tid >> 6, lane = tid & 63;
    const int quad = lane >> 4, l16 = lane & 15;
    const int bh = blockIdx.x & 31;          // xcd = bh % 8 -> K/V L2-resident per XCD
    const int b = bh >> 3, h = bh & 7;
    const int q0 = (blockIdx.x >> 5) * 16;   // 64 q-tiles of 16 rows

    const unsigned short* qp = Qb + ((size_t)bh * 1024 + q0 + l16) * 64 + quad * 8;
    bf16x8 qf0 = *(const bf16x8*)qp;
    bf16x8 qf1 = *(const bf16x8*)(qp + 32);

    // K frag (MFMA A): m=l16 -> key row, k=quad*8+j -> d
    const unsigned short* kbase = Kb + ((size_t)bh * 1024 + l16) * 64 + quad * 8;
    // V frag (MFMA B): n=l16 -> d, k=quad*8+j -> t
    const unsigned short* vbase = Vt + ((size_t)bh * 64 + l16) * 1024 + quad * 8;

    // bpermute byte addresses: pull from quad (2q)&3 / (2q+1)&3 at same l16
    const int sA  = ((((2 * quad) & 3) << 4) + l16) << 2;
    const int sB2 = ((((2 * quad + 1) & 3) << 4) + l16) << 2;

    f32x4 o[4];
#pragma unroll
    for (int nf = 0; nf < 4; ++nf) o[nf] = (f32x4){0.f, 0.f, 0.f, 0.f};
    float lp = 0.f;   // per-lane partial column (=query) sum

    const int j0 = wave * 256;
    for (int jt = j0; jt < j0 + 256; jt += 64) {
        // ---- K frags for this tile ----
        bf16x8 kc[8];
#pragma unroll
        for (int nf = 0; nf < 4; ++nf) {
            kc[2 * nf]     = *(const bf16x8*)(kbase + (size_t)jt * 64 + nf * 1024);
            kc[2 * nf + 1] = *(const bf16x8*)(kbase + (size_t)jt * 64 + nf * 1024 + 32);
        }
        // ---- S^T tiles: row = key (quad*4+r within tile nf), col = query (l16) ----
        f32x4 s[4];
#pragma unroll
        for (int nf = 0; nf < 4; ++nf) {
            f32x4 z = {0.f, 0.f, 0.f, 0.f};
            z = __builtin_amdgcn_mfma_f32_16x16x32_bf16(kc[2 * nf], qf0, z, 0, 0, 0);
            z = __builtin_amdgcn_mfma_f32_16x16x32_bf16(kc[2 * nf + 1], qf1, z, 0, 0, 0);
            s[nf] = z;
        }
        // ---- V loads (vmcnt-tracked, overlap with exp/permute) ----
        bf16x8 vf[8];
#pragma unroll
        for (int nf = 0; nf < 4; ++nf) {
            vf[2 * nf]     = *(const bf16x8*)(vbase + jt + (size_t)nf * 16 * 1024);
            vf[2 * nf + 1] = *(const bf16x8*)(vbase + jt + (size_t)nf * 16 * 1024 + 32);
        }
        // ---- P^T = exp(S^T); pack bf16 pairs per tile ----
        unsigned pk01[4], pk23[4];
#pragma unroll
        for (int nf = 0; nf < 4; ++nf) {
            float p0 = __expf(s[nf][0]);
            float p1 = __expf(s[nf][1]);
            float p2 = __expf(s[nf][2]);
            float p3 = __expf(s[nf][3]);
            lp += (p0 + p1) + (p2 + p3);
            pk01[nf] = pack2(p0, p1);
            pk23[nf] = pack2(p2, p3);
        }
        // ---- register-only C->A transform (validated R7) ----
        union PU { unsigned d[4]; bf16x8 v; } f0, f1;
        {
            unsigned a0, a1;
            a0 = (unsigned)__builtin_amdgcn_ds_bpermute(sA,  (int)pk01[0]);
            a1 = (unsigned)__builtin_amdgcn_ds_bpermute(sA,  (int)pk01[1]);
            f0.d[0] = (quad < 2) ? a0 : a1;
            a0 = (unsigned)__builtin_amdgcn_ds_bpermute(sA,  (int)pk23[0]);
            a1 = (unsigned)__builtin_amdgcn_ds_bpermute(sA,  (int)pk23[1]);
            f0.d[1] = (quad < 2) ? a0 : a1;
            a0 = (unsigned)__builtin_amdgcn_ds_bpermute(sB2, (int)pk01[0]);
            a1 = (unsigned)__builtin_amdgcn_ds_bpermute(sB2, (int)pk01[1]);
            f0.d[2] = (quad < 2) ? a0 : a1;
            a0 = (unsigned)__builtin_amdgcn_ds_bpermute(sB2, (int)pk23[0]);
            a1 = (unsigned)__builtin_amdgcn_ds_bpermute(sB2, (int)pk23[1]);
            f0.d[3] = (quad < 2) ? a0 : a1;
            a0 = (unsigned)__builtin_amdgcn_ds_bpermute(sA,  (int)pk01[2]);
            a1 = (unsigned)__builtin_amdgcn_ds_bpermute(sA,  (int)pk01[3]);
            f1.d[0] = (quad < 2) ? a0 : a1;
            a0 = (unsigned)__builtin_amdgcn_ds_bpermute(sA,  (int)pk23[2]);
            a1 = (unsigned)__builtin_amdgcn_ds_bpermute(sA,  (int)pk23[3]);
            f1.d[1] = (quad < 2) ? a0 : a1;
            a0 = (unsigned)__builtin_amdgcn_ds_bpermute(sB2, (int)pk01[2]);
            a1 = (unsigned)__builtin_amdgcn_ds_bpermute(sB2, (int)pk01[3]);
            f1.d[2] = (quad < 2) ? a0 : a1;
            a0 = (unsigned)__builtin_amdgcn_ds_bpermute(sB2, (int)pk23[2]);
            a1 = (unsigned)__builtin_amdgcn_ds_bpermute(sB2, (int)pk23[3]);
            f1.d[3] = (quad < 2) ? a0 : a1;
        }
        // ---- O += P.V ----
#pragma unroll
        for (int nf = 0; nf < 4; ++nf) {
            o[nf] = __builtin_amdgcn_mfma_f32_16x16x32_bf16(f0.v, vf[2 * nf], o[nf], 0, 0, 0);
            o[nf] = __builtin_amdgcn_mfma_f32_16x16x32_bf16(f1.v, vf[2 * nf + 1], o[nf], 0, 0, 0);
        }
    }
    // ---- write per-wave partials to LDS ----
#pragma unroll
    for (int nf = 0; nf < 4; ++nf)
#pragma unroll
        for (int r = 0; r < 4; ++r)
            Ol[wave][quad * 4 + r][nf * 16 + l16] = o[nf][r];
    float ts = lp;
    ts += __shfl_xor(ts, 16, 64);
    ts += __shfl_xor(ts, 32, 64);
    if (quad == 0) Ls[wave][l16] = ts;
    __syncthreads();
    // ---- combine: wave w handles d-frag nf=w ----
    float denom[4];
#pragma unroll
    for (int r = 0; r < 4; ++r)
        denom[r] = Ls[0][quad * 4 + r] + Ls[1][quad * 4 + r]
                 + Ls[2][quad * 4 + r] + Ls[3][quad * 4 + r];
#pragma unroll
    for (int r = 0; r < 4; ++r) {
        int qq = quad * 4 + r;
        float v = Ol[0][qq][wave * 16 + l16] + Ol[1][qq][wave * 16 + l16]
                + Ol[2][qq][wave * 16 + l16] + Ol[3][qq][wave * 16 + l16];
        int q = q0 + qq;
        av[((size_t)(b * 1024 + q)) * D + h * 64 + wave * 16 + l16] =
            f2bf(v / denom[r]);
    }
}

// ---------------- classifier ----------------
__global__ __launch_bounds__(256) void cls_kernel(
    const float* __restrict__ x, const float* __restrict__ Wc,
    const float* __restrict__ bc, float* __restrict__ out)
{
    int lane = threadIdx.x & 63;
    int row = blockIdx.x * 4 + (threadIdx.x >> 6);
    const float* xr = x + (size_t)row * D + lane * 8;
    float4 v0 = *(const float4*)xr;
    float4 v1 = *(const float4*)(xr + 4);
    float acc[10];
#pragma unroll
    for (int c = 0; c < 10; ++c) {
        const float* wr = Wc + c * D + lane * 8;
        float4 w0 = *(const float4*)wr;
        float4 w1 = *(const float4*)(wr + 4);
        acc[c] = v0.x*w0.x + v0.y*w0.y + v0.z*w0.z + v0.w*w0.w
               + v1.x*w1.x + v1.y*w1.y + v1.z*w1.z + v1.w*w1.w;
    }
#pragma unroll
    for (int c = 0; c < 10; ++c)
#pragma unroll
        for (int off = 32; off; off >>= 1) acc[c] += __shfl_xor(acc[c], off, 64);
    if (lane == 0) {
#pragma unroll
        for (int c = 0; c < 10; ++c) out[(size_t)row * 10 + c] = acc[c] + bc[c];
    }
}

extern "C" void kernel_launch(void* const* d_in, const int* in_sizes, int n_in,
                              void* d_out, int out_size, void* d_ws, size_t ws_size,
                              hipStream_t stream)
{
    const int*   tokens = (const int*)  d_in[0];
    const float* emb    = (const float*)d_in[1];
    const float* Wq     = (const float*)d_in[2];
    const float* bq     = (const float*)d_in[3];
    const float* Wkv    = (const float*)d_in[4];
    const float* bkv    = (const float*)d_in[5];
    const float* Wo     = (const float*)d_in[6];
    const float* bo     = (const float*)d_in[7];
    const float* ln1g   = (const float*)d_in[8];
    const float* ln1b   = (const float*)d_in[9];
    const float* W1     = (const float*)d_in[10];
    const float* b1     = (const float*)d_in[11];
    const float* W2     = (const float*)d_in[12];
    const float* b2     = (const float*)d_in[13];
    const float* ln2g   = (const float*)d_in[14];
    const float* ln2b   = (const float*)d_in[15];
    const float* Wc     = (const float*)d_in[16];
    const float* bc     = (const float*)d_in[17];
    float* out = (float*)d_out;

    // workspace (~34 MB):
    // x fp32 8MB | hb bf16 4MB | Qb 4 | Kb 4 | Vt 4 | avb 4 (f1b 16MB aliases Qb..avb)
    // | wl bf16 6MB | wbias fp32 6KB
    float* x  = (float*)d_ws;
    unsigned short* hb  = (unsigned short*)(x + (size_t)MTOK * D);
    unsigned short* Qb  = hb  + (size_t)MTOK * D;
    unsigned short* Kb  = Qb  + (size_t)32 * 1024 * 64;
    unsigned short* Vt  = Kb  + (size_t)32 * 1024 * 64;
    unsigned short* avb = Vt  + (size_t)32 * 1024 * 64;
    unsigned short* f1b = Qb;                              // [4096][2048] bf16 = 16 MB
    unsigned short* wl  = avb + (size_t)32 * 1024 * 64;    // per-layer bf16 weights (6 MB)
    float* wbias = (float*)(wl + (size_t)3145728);         // combined [bq;bkv] (6 KB)

    // wl layout: [Wq;Wkv] = contiguous 1536x512, then Wo, W1, W2
    const size_t oWo = 786432, oW1 = 1048576, oW2 = 2097152;

    embed_kernel<<<MTOK, 128, 0, stream>>>(tokens, emb, x);

    for (int l = 0; l < NLAYER; ++l) {
        wconv_kernel<<<1537, 256, 0, stream>>>(
            Wq  + (size_t)l * 262144,  Wkv + (size_t)l * 524288,
            Wo  + (size_t)l * 262144,  W1  + (size_t)l * 1048576,
            W2  + (size_t)l * 1048576, bq + (size_t)l * 512,
            bkv + (size_t)l * 1024, wl, wbias);
        ln_kernel<<<MTOK / 4, 256, 0, stream>>>(x, ln1g + l * D, ln1b + l * D, hb);
        gemm_bf16<2,128><<<dim3(12, 32), 256, 0, stream>>>(
            hb, wl, wbias, nullptr, Qb, Kb, Vt, MTOK, 1536, 512);
        attn_mfma<<<2048, 256, 0, stream>>>(Qb, Kb, Vt, avb);
        gemm_bf16<0,64><<<dim3(4, 64), 256, 0, stream>>>(
            avb, wl + oWo, bo + l * D, x, x, nullptr, nullptr, MTOK, D, D);
        ln_kernel<<<MTOK / 4, 256, 0, stream>>>(x, ln2g + l * D, ln2b + l * D, hb);
        gemm_bf16<1,128><<<dim3(16, 32), 256, 0, stream>>>(
            hb, wl + oW1, b1 + l * 4 * D, nullptr, f1b, nullptr, nullptr, MTOK, 4 * D, D);
        gemm_bf16<0,64><<<dim3(4, 64), 256, 0, stream>>>(
            f1b, wl + oW2, b2 + l * D, x, x, nullptr, nullptr, MTOK, D, 4 * D);
    }

    cls_kernel<<<MTOK / 4, 256, 0, stream>>>(x, Wc, bc, out);
}

// Round 9
// 1091.914 us; speedup vs baseline: 1.0076x; 1.0076x over previous
//
#include <hip/hip_runtime.h>
#include <math.h>

#define D 512
#define HEADS 8
#define NLAYER 6
#define LSEQ 1024
#define BATCH 4
#define DKH 64
#define MTOK (BATCH*LSEQ)   // 4096 tokens
#define EPS 1e-5f
#define EMB_SCALE 22.627416997969522f  // sqrt(512)
#define INV_SCALE 0.125f               // 1/sqrt(64)

typedef __attribute__((ext_vector_type(8))) __bf16 bf16x8;
typedef __attribute__((ext_vector_type(4))) float f32x4;

__device__ __forceinline__ unsigned short f2bf(float x) {
    union { float f; unsigned u; } v; v.f = x;
    unsigned r = (v.u + 0x7FFFu + ((v.u >> 16) & 1u)) >> 16;
    return (unsigned short)r;
}
__device__ __forceinline__ unsigned pack2(float a, float b) {
    return (unsigned)f2bf(a) | ((unsigned)f2bf(b) << 16);
}
__device__ __forceinline__ void gl_lds16(const unsigned short* g, unsigned short* l) {
    __builtin_amdgcn_global_load_lds(
        (const __attribute__((address_space(1))) unsigned*)g,
        (__attribute__((address_space(3))) unsigned*)l, 16, 0, 0);
}

// ---------------- embedding + positional encoding (fp32 x) ----------------
__global__ __launch_bounds__(128) void embed_kernel(
    const int* __restrict__ tokens, const float* __restrict__ emb,
    float* __restrict__ x)
{
    int row = blockIdx.x;
    int pos = row & (LSEQ - 1);
    int tok = tokens[row];
    int c = threadIdx.x * 4;
    float4 e = *(const float4*)(emb + (size_t)tok * D + c);
    float o[4] = {e.x, e.y, e.z, e.w};
#pragma unroll
    for (int i = 0; i < 4; ++i) {
        int col = c + i;
        int ii = col & ~1;
        float dv = expf(-(float)ii * (9.210340371976184f / (float)D));
        float a = (float)pos * dv;
        float pe = (col & 1) ? cosf(a) : sinf(a);
        o[i] = o[i] * EMB_SCALE + pe;
    }
    float4 r; r.x = o[0]; r.y = o[1]; r.z = o[2]; r.w = o[3];
    *(float4*)(x + (size_t)row * D + c) = r;
}

// ---------------- layernorm fp32 -> bf16: one wave per row ----------------
__global__ __launch_bounds__(256) void ln_kernel(
    const float* __restrict__ x, const float* __restrict__ g,
    const float* __restrict__ b, unsigned short* __restrict__ h)
{
    int lane = threadIdx.x & 63;
    int row = blockIdx.x * 4 + (threadIdx.x >> 6);
    const float* xr = x + (size_t)row * D + lane * 8;
    float4 v0 = *(const float4*)(xr);
    float4 v1 = *(const float4*)(xr + 4);
    float s = v0.x + v0.y + v0.z + v0.w + v1.x + v1.y + v1.z + v1.w;
#pragma unroll
    for (int off = 32; off; off >>= 1) s += __shfl_xor(s, off, 64);
    float m = s * (1.0f / D);
    float d0 = v0.x - m, d1 = v0.y - m, d2 = v0.z - m, d3 = v0.w - m;
    float d4 = v1.x - m, d5 = v1.y - m, d6 = v1.z - m, d7 = v1.w - m;
    float ss = d0*d0 + d1*d1 + d2*d2 + d3*d3 + d4*d4 + d5*d5 + d6*d6 + d7*d7;
#pragma unroll
    for (int off = 32; off; off >>= 1) ss += __shfl_xor(ss, off, 64);
    float inv = rsqrtf(ss * (1.0f / D) + EPS);
    const float* gp = g + lane * 8;
    const float* bp = b + lane * 8;
    float4 g0 = *(const float4*)(gp), g1 = *(const float4*)(gp + 4);
    float4 b0 = *(const float4*)(bp), b1 = *(const float4*)(bp + 4);
    uint4 o;
    o.x = pack2(d0 * inv * g0.x + b0.x, d1 * inv * g0.y + b0.y);
    o.y = pack2(d2 * inv * g0.z + b0.z, d3 * inv * g0.w + b0.w);
    o.z = pack2(d4 * inv * g1.x + b1.x, d5 * inv * g1.y + b1.y);
    o.w = pack2(d6 * inv * g1.z + b1.z, d7 * inv * g1.w + b1.w);
    *(uint4*)(h + (size_t)row * D + lane * 8) = o;
}

// ---------------- per-layer weight fp32 -> bf16 (+ combined QKV bias) ----------------
__global__ __launch_bounds__(256) void wconv_kernel(
    const float* __restrict__ Wq, const float* __restrict__ Wkv,
    const float* __restrict__ Wo, const float* __restrict__ W1,
    const float* __restrict__ W2, const float* __restrict__ bq,
    const float* __restrict__ bkv, unsigned short* __restrict__ dst,
    float* __restrict__ bias_out)
{
    if (blockIdx.x == 1536) {
        for (int i = threadIdx.x; i < 1536; i += 256)
            bias_out[i] = (i < 512) ? bq[i] : bkv[i - 512];
        return;
    }
    int gid = blockIdx.x * 256 + threadIdx.x;
    int e = gid * 8;
    const float* src;
    if      (e < 262144)  src = Wq  + e;
    else if (e < 786432)  src = Wkv + (e - 262144);
    else if (e < 1048576) src = Wo  + (e - 786432);
    else if (e < 2097152) src = W1  + (e - 1048576);
    else                  src = W2  + (e - 2097152);
    float4 a = *(const float4*)src;
    float4 b = *(const float4*)(src + 4);
    uint4 o;
    o.x = pack2(a.x, a.y); o.y = pack2(a.z, a.w);
    o.z = pack2(b.x, b.y); o.w = pack2(b.z, b.w);
    *(uint4*)(dst + e) = o;
}

// ---------------- bf16 MFMA GEMM: acc = A(bf16 MxK) @ W(bf16 NxK)^T ----------------
// Tile BM x 128, BK=32, 256 threads. BM=128: waves 2x2 (64x64 each);
// BM=64: waves 1x4 (64x32 each).
// OMODE 0: C fp32 [M][N] = acc + bias + X (residual)
// OMODE 1: C bf16 [M][N] = relu(acc + bias)
// OMODE 2: fused QKV (N=1536): c<512 -> C=Qb[bh][t][64] scaled;
//          512<=c<1024 -> C2=Kb[bh][t][64]; c>=1024 -> C3=Vt[bh][d][t]
template<int OMODE, int BM>
__global__ __launch_bounds__(256) void gemm_bf16(
    const unsigned short* __restrict__ A, const unsigned short* __restrict__ W,
    const float* __restrict__ bias, const float* __restrict__ X,
    void* __restrict__ C, void* __restrict__ C2, void* __restrict__ C3,
    int M, int N, int K)
{
    constexpr int WM = BM / 64;       // 2 or 1
    constexpr int WN = 4 / WM;        // 2 or 4
    constexpr int NI = 8 / WN;        // 4 or 2 (16-col frags per wave)
    __shared__ unsigned short As[BM * 32];
    __shared__ unsigned short Bs[128 * 32];
    const int tid = threadIdx.x;
    const int wave = tid >> 6, lane = tid & 63;
    const int quad = lane >> 4, l16 = lane & 15;
    const int wm = wave / WN, wn = wave % WN;
    const int bm = blockIdx.y * BM, bn = blockIdx.x * 128;

    const int srow = wave * 16 + (lane >> 2);
    const int scol = (lane & 3) * 8;
    const unsigned short* Ag0 = A + (size_t)(bm + srow) * K + scol;
    const unsigned short* Ag1 = Ag0 + (size_t)64 * K;
    const unsigned short* Wg0 = W + (size_t)(bn + srow) * K + scol;
    const unsigned short* Wg1 = Wg0 + (size_t)64 * K;
    unsigned short* Al0 = As + wave * 512 + lane * 8;
    unsigned short* Al1 = Al0 + 2048;
    unsigned short* Bl0 = Bs + wave * 512 + lane * 8;
    unsigned short* Bl1 = Bl0 + 2048;

    f32x4 acc[4][NI];
#pragma unroll
    for (int mi = 0; mi < 4; ++mi)
#pragma unroll
        for (int ni = 0; ni < NI; ++ni) acc[mi][ni] = (f32x4){0.f, 0.f, 0.f, 0.f};

    for (int k0 = 0; k0 < K; k0 += 32) {
        __syncthreads();
        gl_lds16(Ag0 + k0, Al0);
        if (BM == 128) gl_lds16(Ag1 + k0, Al1);
        gl_lds16(Wg0 + k0, Bl0);
        gl_lds16(Wg1 + k0, Bl1);
        __syncthreads();
        bf16x8 af[4], bf[NI];
#pragma unroll
        for (int mi = 0; mi < 4; ++mi)
            af[mi] = *(const bf16x8*)(As + (wm * 64 + mi * 16 + l16) * 32 + quad * 8);
#pragma unroll
        for (int ni = 0; ni < NI; ++ni)
            bf[ni] = *(const bf16x8*)(Bs + (wn * (128 / WN) + ni * 16 + l16) * 32 + quad * 8);
#pragma unroll
        for (int mi = 0; mi < 4; ++mi)
#pragma unroll
            for (int ni = 0; ni < NI; ++ni)
                acc[mi][ni] = __builtin_amdgcn_mfma_f32_16x16x32_bf16(
                    af[mi], bf[ni], acc[mi][ni], 0, 0, 0);
    }

    const int er = bm + wm * 64;
    const int ec = bn + wn * (128 / WN);

    if (OMODE == 0) {
        float* Cf = (float*)C;
#pragma unroll
        for (int ni = 0; ni < NI; ++ni) {
            int c = ec + ni * 16 + l16;
            float bv = bias[c];
#pragma unroll
            for (int mi = 0; mi < 4; ++mi)
#pragma unroll
                for (int r = 0; r < 4; ++r) {
                    int m = er + mi * 16 + quad * 4 + r;
                    Cf[(size_t)m * N + c] = acc[mi][ni][r] + bv + X[(size_t)m * N + c];
                }
        }
    } else if (OMODE == 1) {
        unsigned short* Cb = (unsigned short*)C;
#pragma unroll
        for (int ni = 0; ni < NI; ++ni) {
            int c = ec + ni * 16 + l16;
            float bv = bias[c];
#pragma unroll
            for (int mi = 0; mi < 4; ++mi)
#pragma unroll
                for (int r = 0; r < 4; ++r) {
                    int m = er + mi * 16 + quad * 4 + r;
                    Cb[(size_t)m * N + c] = f2bf(fmaxf(acc[mi][ni][r] + bv, 0.f));
                }
        }
    } else {
        if (bn < 512) {            // Q (scaled)
            unsigned short* Qb = (unsigned short*)C;
#pragma unroll
            for (int ni = 0; ni < NI; ++ni) {
                int c = ec + ni * 16 + l16;
                float bv = bias[c];
                int hh = c >> 6, dd = c & 63;
#pragma unroll
                for (int mi = 0; mi < 4; ++mi)
#pragma unroll
                    for (int r = 0; r < 4; ++r) {
                        int m = er + mi * 16 + quad * 4 + r;
                        int b = m >> 10, t = m & 1023;
                        Qb[((size_t)(b * 8 + hh) * 1024 + t) * 64 + dd] =
                            f2bf((acc[mi][ni][r] + bv) * INV_SCALE);
                    }
            }
        } else if (bn < 1024) {    // K
            unsigned short* Kb = (unsigned short*)C2;
#pragma unroll
            for (int ni = 0; ni < NI; ++ni) {
                int c = ec + ni * 16 + l16;
                float bv = bias[c];
                int c2 = c - 512;
                int hh = c2 >> 6, dd = c2 & 63;
#pragma unroll
                for (int mi = 0; mi < 4; ++mi)
#pragma unroll
                    for (int r = 0; r < 4; ++r) {
                        int m = er + mi * 16 + quad * 4 + r;
                        int b = m >> 10, t = m & 1023;
                        Kb[((size_t)(b * 8 + hh) * 1024 + t) * 64 + dd] =
                            f2bf(acc[mi][ni][r] + bv);
                    }
            }
        } else {                   // V transposed
            unsigned short* Vt = (unsigned short*)C3;
#pragma unroll
            for (int ni = 0; ni < NI; ++ni) {
                int c = ec + ni * 16 + l16;
                float bv = bias[c];
                int c2 = c - 1024;
                int hh = c2 >> 6, dd = c2 & 63;
#pragma unroll
                for (int mi = 0; mi < 4; ++mi) {
                    int t0 = er + mi * 16 + quad * 4;
                    int b = t0 >> 10, tt = t0 & 1023;
                    ushort4 o;
                    o.x = f2bf(acc[mi][ni][0] + bv);
                    o.y = f2bf(acc[mi][ni][1] + bv);
                    o.z = f2bf(acc[mi][ni][2] + bv);
                    o.w = f2bf(acc[mi][ni][3] + bv);
                    *(ushort4*)(Vt + ((size_t)(b * 8 + hh) * 64 + dd) * 1024 + tt) = o;
                }
            }
        }
    }
}

// ---------------- flash attention: split-K, MLP-pipelined ----------------
// Qb,Kb: [32][1024][64] bf16 (Q pre-scaled); Vt: [32][64][1024] bf16.
// Block = 16 q-rows of one bh; wave w processes keys [w*256, w*256+256).
// Grid 2048 (bh = blockIdx%32 keeps K/V L2-resident per XCD).
// __launch_bounds__(256,1): allow high VGPR so K/V frag double-buffers stay
// live -> the 16 loads/iter issue in PARALLEL (R8 had VGPR=56: loads were
// compiler-serialized at ~900cyc each = the invariant 65us). Fully unrolled
// modulo pipeline: iter i+1 loads issued before iter i compute.
__global__ __launch_bounds__(256, 1) void attn_mfma(
    const unsigned short* __restrict__ Qb, const unsigned short* __restrict__ Kb,
    const unsigned short* __restrict__ Vt, unsigned short* __restrict__ av)
{
    __shared__ float Ol[4][16][68];   // [wave][q][d] fp32 partial O (+pad)
    __shared__ float Ls[4][16];       // [wave][q] partial denominators
    const int tid = threadIdx.x;
    const int wave = tid >> 6, lane = tid & 63;
    const int quad = lane >> 4, l16 = lane & 15;
    const int bh = blockIdx.x & 31;          // xcd = bh % 8 -> K/V L2-resident per XCD
    const int b = bh >> 3, h = bh & 7;
    const int q0 = (blockIdx.x >> 5) * 16;   // 64 q-tiles of 16 rows

    const unsigned short* qp = Qb + ((size_t)bh * 1024 + q0 + l16) * 64 + quad * 8;
    bf16x8 qf0 = *(const bf16x8*)qp;
    bf16x8 qf1 = *(const bf16x8*)(qp + 32);

    // K frag (MFMA A): m=l16 -> key row, k=quad*8+j -> d
    const unsigned short* kbase = Kb + ((size_t)bh * 1024 + l16) * 64 + quad * 8;
    // V frag (MFMA B): n=l16 -> d, k=quad*8+j -> t
    const unsigned short* vbase = Vt + ((size_t)bh * 64 + l16) * 1024 + quad * 8;

    // bpermute byte addresses: pull from quad (2q)&3 / (2q+1)&3 at same l16
    const int sA  = ((((2 * quad) & 3) << 4) + l16) << 2;
    const int sB2 = ((((2 * quad + 1) & 3) << 4) + l16) << 2;

    f32x4 o[4];
#pragma unroll
    for (int nf = 0; nf < 4; ++nf) o[nf] = (f32x4){0.f, 0.f, 0.f, 0.f};
    float lp = 0.f;   // per-lane partial column (=query) sum

    const int j0 = wave * 256;

    // double-buffered K/V fragment registers (2 x 16 x 4 VGPR = 128 VGPR)
    bf16x8 kc[2][8], vf[2][8];
#pragma unroll
    for (int nf = 0; nf < 4; ++nf) {
        kc[0][2 * nf]     = *(const bf16x8*)(kbase + (size_t)j0 * 64 + nf * 1024);
        kc[0][2 * nf + 1] = *(const bf16x8*)(kbase + (size_t)j0 * 64 + nf * 1024 + 32);
        vf[0][2 * nf]     = *(const bf16x8*)(vbase + j0 + (size_t)nf * 16 * 1024);
        vf[0][2 * nf + 1] = *(const bf16x8*)(vbase + j0 + (size_t)nf * 16 * 1024 + 32);
    }

#pragma unroll
    for (int it = 0; it < 4; ++it) {
        const int cur = it & 1, nxt = cur ^ 1;
        // ---- issue next tile's 16 loads BEFORE current compute ----
        if (it < 3) {
            const int jn = j0 + (it + 1) * 64;
#pragma unroll
            for (int nf = 0; nf < 4; ++nf) {
                kc[nxt][2 * nf]     = *(const bf16x8*)(kbase + (size_t)jn * 64 + nf * 1024);
                kc[nxt][2 * nf + 1] = *(const bf16x8*)(kbase + (size_t)jn * 64 + nf * 1024 + 32);
                vf[nxt][2 * nf]     = *(const bf16x8*)(vbase + jn + (size_t)nf * 16 * 1024);
                vf[nxt][2 * nf + 1] = *(const bf16x8*)(vbase + jn + (size_t)nf * 16 * 1024 + 32);
            }
        }
        // ---- S^T tiles: row = key (quad*4+r within tile nf), col = query (l16) ----
        f32x4 s[4];
#pragma unroll
        for (int nf = 0; nf < 4; ++nf) {
            f32x4 z = {0.f, 0.f, 0.f, 0.f};
            z = __builtin_amdgcn_mfma_f32_16x16x32_bf16(kc[cur][2 * nf], qf0, z, 0, 0, 0);
            z = __builtin_amdgcn_mfma_f32_16x16x32_bf16(kc[cur][2 * nf + 1], qf1, z, 0, 0, 0);
            s[nf] = z;
        }
        // ---- P^T = exp(S^T); pack bf16 pairs per tile ----
        unsigned pk01[4], pk23[4];
#pragma unroll
        for (int nf = 0; nf < 4; ++nf) {
            float p0 = __expf(s[nf][0]);
            float p1 = __expf(s[nf][1]);
            float p2 = __expf(s[nf][2]);
            float p3 = __expf(s[nf][3]);
            lp += (p0 + p1) + (p2 + p3);
            pk01[nf] = pack2(p0, p1);
            pk23[nf] = pack2(p2, p3);
        }
        // ---- register-only C->A transform (validated R7) ----
        union PU { unsigned d[4]; bf16x8 v; } f0, f1;
        {
            unsigned a0, a1;
            a0 = (unsigned)__builtin_amdgcn_ds_bpermute(sA,  (int)pk01[0]);
            a1 = (unsigned)__builtin_amdgcn_ds_bpermute(sA,  (int)pk01[1]);
            f0.d[0] = (quad < 2) ? a0 : a1;
            a0 = (unsigned)__builtin_amdgcn_ds_bpermute(sA,  (int)pk23[0]);
            a1 = (unsigned)__builtin_amdgcn_ds_bpermute(sA,  (int)pk23[1]);
            f0.d[1] = (quad < 2) ? a0 : a1;
            a0 = (unsigned)__builtin_amdgcn_ds_bpermute(sB2, (int)pk01[0]);
            a1 = (unsigned)__builtin_amdgcn_ds_bpermute(sB2, (int)pk01[1]);
            f0.d[2] = (quad < 2) ? a0 : a1;
            a0 = (unsigned)__builtin_amdgcn_ds_bpermute(sB2, (int)pk23[0]);
            a1 = (unsigned)__builtin_amdgcn_ds_bpermute(sB2, (int)pk23[1]);
            f0.d[3] = (quad < 2) ? a0 : a1;
            a0 = (unsigned)__builtin_amdgcn_ds_bpermute(sA,  (int)pk01[2]);
            a1 = (unsigned)__builtin_amdgcn_ds_bpermute(sA,  (int)pk01[3]);
            f1.d[0] = (quad < 2) ? a0 : a1;
            a0 = (unsigned)__builtin_amdgcn_ds_bpermute(sA,  (int)pk23[2]);
            a1 = (unsigned)__builtin_amdgcn_ds_bpermute(sA,  (int)pk23[3]);
            f1.d[1] = (quad < 2) ? a0 : a1;
            a0 = (unsigned)__builtin_amdgcn_ds_bpermute(sB2, (int)pk01[2]);
            a1 = (unsigned)__builtin_amdgcn_ds_bpermute(sB2, (int)pk01[3]);
            f1.d[2] = (quad < 2) ? a0 : a1;
            a0 = (unsigned)__builtin_amdgcn_ds_bpermute(sB2, (int)pk23[2]);
            a1 = (unsigned)__builtin_amdgcn_ds_bpermute(sB2, (int)pk23[3]);
            f1.d[3] = (quad < 2) ? a0 : a1;
        }
        // ---- O += P.V ----
#pragma unroll
        for (int nf = 0; nf < 4; ++nf) {
            o[nf] = __builtin_amdgcn_mfma_f32_16x16x32_bf16(f0.v, vf[cur][2 * nf], o[nf], 0, 0, 0);
            o[nf] = __builtin_amdgcn_mfma_f32_16x16x32_bf16(f1.v, vf[cur][2 * nf + 1], o[nf], 0, 0, 0);
        }
    }
    // ---- write per-wave partials to LDS ----
#pragma unroll
    for (int nf = 0; nf < 4; ++nf)
#pragma unroll
        for (int r = 0; r < 4; ++r)
            Ol[wave][quad * 4 + r][nf * 16 + l16] = o[nf][r];
    float ts = lp;
    ts += __shfl_xor(ts, 16, 64);
    ts += __shfl_xor(ts, 32, 64);
    if (quad == 0) Ls[wave][l16] = ts;
    __syncthreads();
    // ---- combine: wave w handles d-frag nf=w ----
    float denom[4];
#pragma unroll
    for (int r = 0; r < 4; ++r)
        denom[r] = Ls[0][quad * 4 + r] + Ls[1][quad * 4 + r]
                 + Ls[2][quad * 4 + r] + Ls[3][quad * 4 + r];
#pragma unroll
    for (int r = 0; r < 4; ++r) {
        int qq = quad * 4 + r;
        float v = Ol[0][qq][wave * 16 + l16] + Ol[1][qq][wave * 16 + l16]
                + Ol[2][qq][wave * 16 + l16] + Ol[3][qq][wave * 16 + l16];
        int q = q0 + qq;
        av[((size_t)(b * 1024 + q)) * D + h * 64 + wave * 16 + l16] =
            f2bf(v / denom[r]);
    }
}

// ---------------- classifier ----------------
__global__ __launch_bounds__(256) void cls_kernel(
    const float* __restrict__ x, const float* __restrict__ Wc,
    const float* __restrict__ bc, float* __restrict__ out)
{
    int lane = threadIdx.x & 63;
    int row = blockIdx.x * 4 + (threadIdx.x >> 6);
    const float* xr = x + (size_t)row * D + lane * 8;
    float4 v0 = *(const float4*)xr;
    float4 v1 = *(const float4*)(xr + 4);
    float acc[10];
#pragma unroll
    for (int c = 0; c < 10; ++c) {
        const float* wr = Wc + c * D + lane * 8;
        float4 w0 = *(const float4*)wr;
        float4 w1 = *(const float4*)(wr + 4);
        acc[c] = v0.x*w0.x + v0.y*w0.y + v0.z*w0.z + v0.w*w0.w
               + v1.x*w1.x + v1.y*w1.y + v1.z*w1.z + v1.w*w1.w;
    }
#pragma unroll
    for (int c = 0; c < 10; ++c)
#pragma unroll
        for (int off = 32; off; off >>= 1) acc[c] += __shfl_xor(acc[c], off, 64);
    if (lane == 0) {
#pragma unroll
        for (int c = 0; c < 10; ++c) out[(size_t)row * 10 + c] = acc[c] + bc[c];
    }
}

extern "C" void kernel_launch(void* const* d_in, const int* in_sizes, int n_in,
                              void* d_out, int out_size, void* d_ws, size_t ws_size,
                              hipStream_t stream)
{
    const int*   tokens = (const int*)  d_in[0];
    const float* emb    = (const float*)d_in[1];
    const float* Wq     = (const float*)d_in[2];
    const float* bq     = (const float*)d_in[3];
    const float* Wkv    = (const float*)d_in[4];
    const float* bkv    = (const float*)d_in[5];
    const float* Wo     = (const float*)d_in[6];
    const float* bo     = (const float*)d_in[7];
    const float* ln1g   = (const float*)d_in[8];
    const float* ln1b   = (const float*)d_in[9];
    const float* W1     = (const float*)d_in[10];
    const float* b1     = (const float*)d_in[11];
    const float* W2     = (const float*)d_in[12];
    const float* b2     = (const float*)d_in[13];
    const float* ln2g   = (const float*)d_in[14];
    const float* ln2b   = (const float*)d_in[15];
    const float* Wc     = (const float*)d_in[16];
    const float* bc     = (const float*)d_in[17];
    float* out = (float*)d_out;

    // workspace (~34 MB):
    // x fp32 8MB | hb bf16 4MB | Qb 4 | Kb 4 | Vt 4 | avb 4 (f1b 16MB aliases Qb..avb)
    // | wl bf16 6MB | wbias fp32 6KB
    float* x  = (float*)d_ws;
    unsigned short* hb  = (unsigned short*)(x + (size_t)MTOK * D);
    unsigned short* Qb  = hb  + (size_t)MTOK * D;
    unsigned short* Kb  = Qb  + (size_t)32 * 1024 * 64;
    unsigned short* Vt  = Kb  + (size_t)32 * 1024 * 64;
    unsigned short* avb = Vt  + (size_t)32 * 1024 * 64;
    unsigned short* f1b = Qb;                              // [4096][2048] bf16 = 16 MB
    unsigned short* wl  = avb + (size_t)32 * 1024 * 64;    // per-layer bf16 weights (6 MB)
    float* wbias = (float*)(wl + (size_t)3145728);         // combined [bq;bkv] (6 KB)

    // wl layout: [Wq;Wkv] = contiguous 1536x512, then Wo, W1, W2
    const size_t oWo = 786432, oW1 = 1048576, oW2 = 2097152;

    embed_kernel<<<MTOK, 128, 0, stream>>>(tokens, emb, x);

    for (int l = 0; l < NLAYER; ++l) {
        wconv_kernel<<<1537, 256, 0, stream>>>(
            Wq  + (size_t)l * 262144,  Wkv + (size_t)l * 524288,
            Wo  + (size_t)l * 262144,  W1  + (size_t)l * 1048576,
            W2  + (size_t)l * 1048576, bq + (size_t)l * 512,
            bkv + (size_t)l * 1024, wl, wbias);
        ln_kernel<<<MTOK / 4, 256, 0, stream>>>(x, ln1g + l * D, ln1b + l * D, hb);
        gemm_bf16<2,128><<<dim3(12, 32), 256, 0, stream>>>(
            hb, wl, wbias, nullptr, Qb, Kb, Vt, MTOK, 1536, 512);
        attn_mfma<<<2048, 256, 0, stream>>>(Qb, Kb, Vt, avb);
        gemm_bf16<0,64><<<dim3(4, 64), 256, 0, stream>>>(
            avb, wl + oWo, bo + l * D, x, x, nullptr, nullptr, MTOK, D, D);
        ln_kernel<<<MTOK / 4, 256, 0, stream>>>(x, ln2g + l * D, ln2b + l * D, hb);
        gemm_bf16<1,128><<<dim3(16, 32), 256, 0, stream>>>(
            hb, wl + oW1, b1 + l * 4 * D, nullptr, f1b, nullptr, nullptr, MTOK, 4 * D, D);
        gemm_bf16<0,64><<<dim3(4, 64), 256, 0, stream>>>(
            f1b, wl + oW2, b2 + l * D, x, x, nullptr, nullptr, MTOK, D, 4 * D);
    }

    cls_kernel<<<MTOK / 4, 256, 0, stream>>>(x, Wc, bc, out);
}